// Round 1
// baseline (602.827 us; speedup 1.0000x reference)
//
#include <hip/hip_runtime.h>
#include <hip/hip_bf16.h>
#include <stdint.h>

typedef __attribute__((ext_vector_type(8))) short short8;
typedef __attribute__((ext_vector_type(4))) float floatx4;

#define MODE_PROJ_T 0  // bf16 out, +bias, transposed per-batch store
#define MODE_PROJ_N 1  // bf16 out, +bias, normal store
#define MODE_SCORES 2  // f32 out, *alpha, no bias, batched
#define MODE_ATT    3  // bf16 out, no bias, batched
#define MODE_OUT    4  // f32 out, +bias, normal

__device__ __forceinline__ unsigned short f2bf(float f) {
    union { float f; unsigned int u; } x; x.f = f;
    unsigned int u = x.u + 0x7FFFu + ((x.u >> 16) & 1u);  // RNE
    return (unsigned short)(u >> 16);
}

__device__ __forceinline__ void gload_lds16(const void* g, void* lds) {
    __builtin_amdgcn_global_load_lds(
        (const __attribute__((address_space(1))) unsigned int*)g,
        (__attribute__((address_space(3))) unsigned int*)lds,
        16, 0, 0);
}

// C[m,n] = alpha * sum_k A[m,k]*B[n,k] (+ bias[n])   -- NT GEMM, all dims %128==0, K%64==0, ld=1024
template<int MODE>
__global__ __launch_bounds__(256) void gemm_nt(
    const __hip_bfloat16* __restrict__ A,
    const __hip_bfloat16* __restrict__ Bm,
    const float* __restrict__ bias,
    void* __restrict__ Cout,
    int K, long sA, long sB, long sC, float alpha)
{
    __shared__ short As[128 * 64];
    __shared__ short Bs[128 * 64];

    const int tid  = threadIdx.x;
    const int wid  = tid >> 6;
    const int lane = tid & 63;
    const int bz   = blockIdx.z;
    const int row0 = blockIdx.y * 128;
    const int col0 = blockIdx.x * 128;

    const __hip_bfloat16* Ab = A  + (size_t)bz * sA;
    const __hip_bfloat16* Bb = Bm + (size_t)bz * sB;

    floatx4 acc[4][4];
#pragma unroll
    for (int i = 0; i < 4; i++)
#pragma unroll
        for (int j = 0; j < 4; j++) acc[i][j] = (floatx4){0.f, 0.f, 0.f, 0.f};

    const int l7   = lane & 7;
    const int l3   = lane >> 3;            // 0..7
    const int cblk = ((l7 ^ l3) << 3);     // swizzled k-block (elements)
    const int wm   = wid >> 1, wn = wid & 1;
    const int l15  = lane & 15, quad = lane >> 4;

    for (int k0 = 0; k0 < K; k0 += 64) {
        __syncthreads();   // previous tile's compute done before overwrite
#pragma unroll
        for (int i = 0; i < 4; i++) {
            const int c = wid * 4 + i;        // chunk 0..15, 8 rows each
            const int r = c * 8 + l3;
            gload_lds16(Ab + (size_t)(row0 + r) * 1024 + k0 + cblk, As + c * 512);
            gload_lds16(Bb + (size_t)(col0 + r) * 1024 + k0 + cblk, Bs + c * 512);
        }
        __syncthreads();   // staging visible
#pragma unroll
        for (int ks = 0; ks < 2; ks++) {
            short8 af[4], bfr[4];
            const int kb = (((ks * 4 + quad) ^ l7) << 3);   // row&7 == l7 for all tiles
#pragma unroll
            for (int t = 0; t < 4; t++) {
                af[t]  = *(const short8*)&As[(wm * 64 + t * 16 + l15) * 64 + kb];
                bfr[t] = *(const short8*)&Bs[(wn * 64 + t * 16 + l15) * 64 + kb];
            }
#pragma unroll
            for (int mt = 0; mt < 4; mt++)
#pragma unroll
                for (int nt = 0; nt < 4; nt++)
                    acc[mt][nt] = __builtin_amdgcn_mfma_f32_16x16x32_bf16(
                        af[mt], bfr[nt], acc[mt][nt], 0, 0, 0);
        }
    }

    // epilogue: C/D layout col=lane&15, row=quad*4+reg  [m89/m91-verified]
#pragma unroll
    for (int nt = 0; nt < 4; nt++) {
        const int col = col0 + wn * 64 + nt * 16 + l15;
        float bv = 0.f;
        if (MODE == MODE_PROJ_T || MODE == MODE_PROJ_N || MODE == MODE_OUT) bv = bias[col];
#pragma unroll
        for (int mt = 0; mt < 4; mt++) {
            const int rbase = row0 + wm * 64 + mt * 16 + quad * 4;
#pragma unroll
            for (int r = 0; r < 4; r++) {
                const int m = rbase + r;
                float v = acc[mt][nt][r];
                if (MODE == MODE_SCORES) v *= alpha;
                v += bv;
                if (MODE == MODE_SCORES) {
                    ((float*)Cout)[(size_t)bz * sC + (size_t)m * 1024 + col] = v;
                } else if (MODE == MODE_OUT) {
                    ((float*)Cout)[(size_t)m * 1024 + col] = v;
                } else if (MODE == MODE_PROJ_N || MODE == MODE_ATT) {
                    ((unsigned short*)Cout)[(size_t)bz * sC + (size_t)m * 1024 + col] = f2bf(v);
                } else { // MODE_PROJ_T: [b, col, m&1023]
                    ((unsigned short*)Cout)[((size_t)(m >> 10) << 20) + (size_t)col * 1024 + (m & 1023)] = f2bf(v);
                }
            }
        }
    }
}

// one wave per 1024-float row; 4 rows per 256-thread block
__global__ __launch_bounds__(256) void softmax_rows(
    const float* __restrict__ S, unsigned short* __restrict__ A)
{
    const int row  = blockIdx.x * 4 + (threadIdx.x >> 6);
    const int lane = threadIdx.x & 63;
    const float4* p = (const float4*)(S + (size_t)row * 1024);
    float4 v[4];
    float mx = -3.0e38f;
#pragma unroll
    for (int i = 0; i < 4; i++) {
        v[i] = p[lane + i * 64];
        mx = fmaxf(mx, fmaxf(fmaxf(v[i].x, v[i].y), fmaxf(v[i].z, v[i].w)));
    }
#pragma unroll
    for (int off = 32; off >= 1; off >>= 1) mx = fmaxf(mx, __shfl_xor(mx, off, 64));
    float e[16], sum = 0.f;
#pragma unroll
    for (int i = 0; i < 4; i++) {
        e[i*4+0] = __expf(v[i].x - mx); e[i*4+1] = __expf(v[i].y - mx);
        e[i*4+2] = __expf(v[i].z - mx); e[i*4+3] = __expf(v[i].w - mx);
        sum += e[i*4+0] + e[i*4+1] + e[i*4+2] + e[i*4+3];
    }
#pragma unroll
    for (int off = 32; off >= 1; off >>= 1) sum += __shfl_xor(sum, off, 64);
    const float inv = 1.0f / sum;
    ushort4* out = (ushort4*)(A + (size_t)row * 1024);
#pragma unroll
    for (int i = 0; i < 4; i++) {
        ushort4 o;
        o.x = f2bf(e[i*4+0] * inv); o.y = f2bf(e[i*4+1] * inv);
        o.z = f2bf(e[i*4+2] * inv); o.w = f2bf(e[i*4+3] * inv);
        out[lane + i * 64] = o;
    }
}

__global__ __launch_bounds__(256) void cvt_bf16(
    const float* __restrict__ in, unsigned short* __restrict__ out, int n4)
{
    const int i = blockIdx.x * 256 + threadIdx.x;
    if (i >= n4) return;
    const float4 v = ((const float4*)in)[i];
    ushort4 o; o.x = f2bf(v.x); o.y = f2bf(v.y); o.z = f2bf(v.z); o.w = f2bf(v.w);
    ((ushort4*)out)[i] = o;
}

extern "C" void kernel_launch(void* const* d_in, const int* in_sizes, int n_in,
                              void* d_out, int out_size, void* d_ws, size_t ws_size,
                              hipStream_t stream) {
    const float* query = (const float*)d_in[0];
    const float* key   = (const float*)d_in[1];
    const float* value = (const float*)d_in[2];
    const float* Wq = (const float*)d_in[3];  const float* bq = (const float*)d_in[4];
    const float* Wk = (const float*)d_in[5];  const float* bk = (const float*)d_in[6];
    const float* Wv = (const float*)d_in[7];  const float* bv = (const float*)d_in[8];
    const float* Wo = (const float*)d_in[9];  const float* bo = (const float*)d_in[10];

    char* ws = (char*)d_ws;
    const size_t MB = 1ull << 20;
    unsigned short* qbf = (unsigned short*)(ws + 0   * MB);   // 32MB
    unsigned short* kbf = (unsigned short*)(ws + 32  * MB);   // 32MB
    unsigned short* vbf = (unsigned short*)(ws + 64  * MB);   // 32MB
    unsigned short* wqb = (unsigned short*)(ws + 96  * MB);   // 2MB
    unsigned short* wkb = (unsigned short*)(ws + 98  * MB);
    unsigned short* wvb = (unsigned short*)(ws + 100 * MB);
    unsigned short* wob = (unsigned short*)(ws + 102 * MB);
    unsigned short* qT  = (unsigned short*)(ws + 104 * MB);   // [B,E,T] 32MB
    unsigned short* kp  = (unsigned short*)(ws + 136 * MB);   // [B,S,E] 32MB
    unsigned short* vT  = (unsigned short*)(ws + 168 * MB);   // [B,E,S] 32MB
    float*          sc  = (float*)(ws + 0 * MB);              // overlay qbf+kbf, 64MB
    unsigned short* att = (unsigned short*)(ws + 64 * MB);    // overlay vbf, 32MB
    unsigned short* ob  = (unsigned short*)(ws + 104 * MB);   // overlay qT, 32MB

    const int NM = 16 * 1024 * 1024;
    const long S1M = 1 << 20;
    dim3 blk(256);

    cvt_bf16<<<NM / 4 / 256, blk, 0, stream>>>(query, qbf, NM / 4);
    cvt_bf16<<<NM / 4 / 256, blk, 0, stream>>>(key,   kbf, NM / 4);
    cvt_bf16<<<NM / 4 / 256, blk, 0, stream>>>(value, vbf, NM / 4);
    cvt_bf16<<<1024, blk, 0, stream>>>(Wq, wqb, 1024 * 1024 / 4);
    cvt_bf16<<<1024, blk, 0, stream>>>(Wk, wkb, 1024 * 1024 / 4);
    cvt_bf16<<<1024, blk, 0, stream>>>(Wv, wvb, 1024 * 1024 / 4);
    cvt_bf16<<<1024, blk, 0, stream>>>(Wo, wob, 1024 * 1024 / 4);

    dim3 gproj(8, 128, 1);   // N=1024, M=16384
    gemm_nt<MODE_PROJ_T><<<gproj, blk, 0, stream>>>(
        (const __hip_bfloat16*)qbf, (const __hip_bfloat16*)wqb, bq, qT, 1024, 0, 0, 0, 1.f);
    gemm_nt<MODE_PROJ_N><<<gproj, blk, 0, stream>>>(
        (const __hip_bfloat16*)kbf, (const __hip_bfloat16*)wkb, bk, kp, 1024, 0, 0, 0, 1.f);
    gemm_nt<MODE_PROJ_T><<<gproj, blk, 0, stream>>>(
        (const __hip_bfloat16*)vbf, (const __hip_bfloat16*)wvb, bv, vT, 1024, 0, 0, 0, 1.f);

    dim3 gbat(8, 8, 16);     // per-batch 1024x1024
    gemm_nt<MODE_SCORES><<<gbat, blk, 0, stream>>>(
        (const __hip_bfloat16*)qT, (const __hip_bfloat16*)kp, nullptr, sc, 1024,
        S1M, S1M, S1M, 0.03125f);

    softmax_rows<<<4096, blk, 0, stream>>>(sc, att);

    gemm_nt<MODE_ATT><<<gbat, blk, 0, stream>>>(
        (const __hip_bfloat16*)att, (const __hip_bfloat16*)vT, nullptr, ob, 1024,
        S1M, S1M, S1M, 1.f);

    gemm_nt<MODE_OUT><<<gproj, blk, 0, stream>>>(
        (const __hip_bfloat16*)ob, (const __hip_bfloat16*)wob, bo, d_out, 1024, 0, 0, 0, 1.f);
}

// Round 2
// 543.356 us; speedup vs baseline: 1.1095x; 1.1095x over previous
//
#include <hip/hip_runtime.h>
#include <hip/hip_bf16.h>
#include <stdint.h>

typedef __attribute__((ext_vector_type(8))) short short8;
typedef __attribute__((ext_vector_type(4))) float floatx4;

#define MODE_PROJ_T 0  // bf16 out, +bias, transposed per-batch store
#define MODE_PROJ_N 1  // bf16 out, +bias, normal store
#define MODE_SCORES 2  // f32 out, *alpha, no bias, batched
#define MODE_ATT    3  // bf16 out, no bias, batched
#define MODE_OUT    4  // f32 out, +bias, normal

__device__ __forceinline__ unsigned short f2bf(float f) {
    union { float f; unsigned int u; } x; x.f = f;
    unsigned int u = x.u + 0x7FFFu + ((x.u >> 16) & 1u);  // RNE
    return (unsigned short)(u >> 16);
}

__device__ __forceinline__ void gload_lds16(const void* g, void* lds) {
    __builtin_amdgcn_global_load_lds(
        (const __attribute__((address_space(1))) unsigned int*)g,
        (__attribute__((address_space(3))) unsigned int*)lds,
        16, 0, 0);
}

// C[m,n] = alpha * sum_k A[m,k]*B[n,k] (+ bias[n])   -- NT GEMM, ld=1024
// Launched as 1D grid of 1024 blocks; block->tile mapping is XCD-aware:
//  proj modes: XCD j owns rows y%8==j for ALL col-blocks (A-tile 8x L2 reuse)
//  batched:    XCD j owns batches z%8==j (whole batch A+B = 4MB in one L2)
template<int MODE>
__global__ __launch_bounds__(256) void gemm_nt(
    const __hip_bfloat16* __restrict__ A,
    const __hip_bfloat16* __restrict__ Bm,
    const float* __restrict__ bias,
    void* __restrict__ Cout,
    int K, long sA, long sB, long sC, float alpha)
{
    __shared__ short As[128 * 64];
    __shared__ short Bs[128 * 64];

    const int tid  = threadIdx.x;
    const int wid  = tid >> 6;
    const int lane = tid & 63;

    // XCD-aware decode (hardware round-robins consecutive block ids across 8 XCDs)
    const int id  = blockIdx.x;
    const int xcd = id & 7;
    const int s   = id >> 3;          // 0..127
    int bx, by, bz;
    if (MODE == MODE_SCORES || MODE == MODE_ATT) {
        bz = xcd + ((s >> 6) << 3);   // batches {j, j+8} on XCD j
        by = (s >> 3) & 7;
        bx = s & 7;
    } else {
        bz = 0;
        bx = s >> 4;                  // 0..7
        by = ((s & 15) << 3) | xcd;   // y%8 == xcd
    }
    const int row0 = by * 128;
    const int col0 = bx * 128;

    const __hip_bfloat16* Ab = A  + (size_t)bz * sA;
    const __hip_bfloat16* Bb = Bm + (size_t)bz * sB;

    floatx4 acc[4][4];
#pragma unroll
    for (int i = 0; i < 4; i++)
#pragma unroll
        for (int j = 0; j < 4; j++) acc[i][j] = (floatx4){0.f, 0.f, 0.f, 0.f};

    const int l7   = lane & 7;
    const int l3   = lane >> 3;            // 0..7
    const int cblk = ((l7 ^ l3) << 3);     // swizzled k-block (elements)
    const int wm   = wid >> 1, wn = wid & 1;
    const int l15  = lane & 15, quad = lane >> 4;

    for (int k0 = 0; k0 < K; k0 += 64) {
        __syncthreads();   // previous tile's compute done before overwrite
#pragma unroll
        for (int i = 0; i < 4; i++) {
            const int c = wid * 4 + i;        // chunk 0..15, 8 rows each
            const int r = c * 8 + l3;
            gload_lds16(Ab + (size_t)(row0 + r) * 1024 + k0 + cblk, As + c * 512);
            gload_lds16(Bb + (size_t)(col0 + r) * 1024 + k0 + cblk, Bs + c * 512);
        }
        __syncthreads();   // staging visible
#pragma unroll
        for (int ks = 0; ks < 2; ks++) {
            short8 af[4], bfr[4];
            const int kb = (((ks * 4 + quad) ^ l7) << 3);   // row&7 == l7 for all tiles
#pragma unroll
            for (int t = 0; t < 4; t++) {
                af[t]  = *(const short8*)&As[(wm * 64 + t * 16 + l15) * 64 + kb];
                bfr[t] = *(const short8*)&Bs[(wn * 64 + t * 16 + l15) * 64 + kb];
            }
#pragma unroll
            for (int mt = 0; mt < 4; mt++)
#pragma unroll
                for (int nt = 0; nt < 4; nt++)
                    acc[mt][nt] = __builtin_amdgcn_mfma_f32_16x16x32_bf16(
                        af[mt], bfr[nt], acc[mt][nt], 0, 0, 0);
        }
    }

    // epilogue: C/D layout col=lane&15, row=quad*4+reg  [m89/m91-verified]
#pragma unroll
    for (int nt = 0; nt < 4; nt++) {
        const int col = col0 + wn * 64 + nt * 16 + l15;
        float bv = 0.f;
        if (MODE == MODE_PROJ_T || MODE == MODE_PROJ_N || MODE == MODE_OUT) bv = bias[col];
#pragma unroll
        for (int mt = 0; mt < 4; mt++) {
            const int rbase = row0 + wm * 64 + mt * 16 + quad * 4;
#pragma unroll
            for (int r = 0; r < 4; r++) {
                const int m = rbase + r;
                float v = acc[mt][nt][r];
                if (MODE == MODE_SCORES) v *= alpha;
                v += bv;
                if (MODE == MODE_SCORES) {
                    ((float*)Cout)[(size_t)bz * sC + (size_t)m * 1024 + col] = v;
                } else if (MODE == MODE_OUT) {
                    ((float*)Cout)[(size_t)m * 1024 + col] = v;
                } else if (MODE == MODE_PROJ_N || MODE == MODE_ATT) {
                    ((unsigned short*)Cout)[(size_t)bz * sC + (size_t)m * 1024 + col] = f2bf(v);
                } else { // MODE_PROJ_T: [b, col, m&1023]
                    ((unsigned short*)Cout)[((size_t)(m >> 10) << 20) + (size_t)col * 1024 + (m & 1023)] = f2bf(v);
                }
            }
        }
    }
}

// one wave per 1024-float row; 4 rows per 256-thread block
__global__ __launch_bounds__(256) void softmax_rows(
    const float* __restrict__ S, unsigned short* __restrict__ A)
{
    const int row  = blockIdx.x * 4 + (threadIdx.x >> 6);
    const int lane = threadIdx.x & 63;
    const float4* p = (const float4*)(S + (size_t)row * 1024);
    float4 v[4];
    float mx = -3.0e38f;
#pragma unroll
    for (int i = 0; i < 4; i++) {
        v[i] = p[lane + i * 64];
        mx = fmaxf(mx, fmaxf(fmaxf(v[i].x, v[i].y), fmaxf(v[i].z, v[i].w)));
    }
#pragma unroll
    for (int off = 32; off >= 1; off >>= 1) mx = fmaxf(mx, __shfl_xor(mx, off, 64));
    float e[16], sum = 0.f;
#pragma unroll
    for (int i = 0; i < 4; i++) {
        e[i*4+0] = __expf(v[i].x - mx); e[i*4+1] = __expf(v[i].y - mx);
        e[i*4+2] = __expf(v[i].z - mx); e[i*4+3] = __expf(v[i].w - mx);
        sum += e[i*4+0] + e[i*4+1] + e[i*4+2] + e[i*4+3];
    }
#pragma unroll
    for (int off = 32; off >= 1; off >>= 1) sum += __shfl_xor(sum, off, 64);
    const float inv = 1.0f / sum;
    ushort4* out = (ushort4*)(A + (size_t)row * 1024);
#pragma unroll
    for (int i = 0; i < 4; i++) {
        ushort4 o;
        o.x = f2bf(e[i*4+0] * inv); o.y = f2bf(e[i*4+1] * inv);
        o.z = f2bf(e[i*4+2] * inv); o.w = f2bf(e[i*4+3] * inv);
        out[lane + i * 64] = o;
    }
}

// all 7 f32->bf16 conversions in ONE dispatch (cuts 6 launch gaps)
__global__ __launch_bounds__(256) void cvt_all(
    const float* __restrict__ q, const float* __restrict__ k, const float* __restrict__ v,
    const float* __restrict__ wq, const float* __restrict__ wk,
    const float* __restrict__ wv, const float* __restrict__ wo,
    unsigned short* __restrict__ qb, unsigned short* __restrict__ kb, unsigned short* __restrict__ vb,
    unsigned short* __restrict__ wqb, unsigned short* __restrict__ wkb,
    unsigned short* __restrict__ wvb, unsigned short* __restrict__ wob)
{
    const int id = blockIdx.x;
    const float* src; unsigned short* dst; int base;
    if      (id < 16384) { src = q;  dst = qb;  base = 0; }
    else if (id < 32768) { src = k;  dst = kb;  base = 16384; }
    else if (id < 49152) { src = v;  dst = vb;  base = 32768; }
    else if (id < 50176) { src = wq; dst = wqb; base = 49152; }
    else if (id < 51200) { src = wk; dst = wkb; base = 50176; }
    else if (id < 52224) { src = wv; dst = wvb; base = 51200; }
    else                 { src = wo; dst = wob; base = 52224; }
    const int i = (id - base) * 256 + threadIdx.x;
    const float4 vv = ((const float4*)src)[i];
    ushort4 o; o.x = f2bf(vv.x); o.y = f2bf(vv.y); o.z = f2bf(vv.z); o.w = f2bf(vv.w);
    ((ushort4*)dst)[i] = o;
}

extern "C" void kernel_launch(void* const* d_in, const int* in_sizes, int n_in,
                              void* d_out, int out_size, void* d_ws, size_t ws_size,
                              hipStream_t stream) {
    const float* query = (const float*)d_in[0];
    const float* key   = (const float*)d_in[1];
    const float* value = (const float*)d_in[2];
    const float* Wq = (const float*)d_in[3];  const float* bq = (const float*)d_in[4];
    const float* Wk = (const float*)d_in[5];  const float* bk = (const float*)d_in[6];
    const float* Wv = (const float*)d_in[7];  const float* bv = (const float*)d_in[8];
    const float* Wo = (const float*)d_in[9];  const float* bo = (const float*)d_in[10];

    char* ws = (char*)d_ws;
    const size_t MB = 1ull << 20;
    unsigned short* qbf = (unsigned short*)(ws + 0   * MB);   // 32MB
    unsigned short* kbf = (unsigned short*)(ws + 32  * MB);   // 32MB
    unsigned short* vbf = (unsigned short*)(ws + 64  * MB);   // 32MB
    unsigned short* wqb = (unsigned short*)(ws + 96  * MB);   // 2MB
    unsigned short* wkb = (unsigned short*)(ws + 98  * MB);
    unsigned short* wvb = (unsigned short*)(ws + 100 * MB);
    unsigned short* wob = (unsigned short*)(ws + 102 * MB);
    unsigned short* qT  = (unsigned short*)(ws + 104 * MB);   // [B,E,T] 32MB
    unsigned short* kp  = (unsigned short*)(ws + 136 * MB);   // [B,S,E] 32MB
    unsigned short* vT  = (unsigned short*)(ws + 168 * MB);   // [B,E,S] 32MB
    float*          sc  = (float*)(ws + 0 * MB);              // overlay qbf+kbf, 64MB
    unsigned short* att = (unsigned short*)(ws + 64 * MB);    // overlay vbf, 32MB
    unsigned short* ob  = (unsigned short*)(ws + 104 * MB);   // overlay qT, 32MB

    const long S1M = 1 << 20;
    dim3 blk(256);

    cvt_all<<<53248, blk, 0, stream>>>(query, key, value, Wq, Wk, Wv, Wo,
                                       qbf, kbf, vbf, wqb, wkb, wvb, wob);

    // projections: M=16384, N=1024, K=1024 (1024 blocks, XCD-swizzled)
    gemm_nt<MODE_PROJ_T><<<1024, blk, 0, stream>>>(
        (const __hip_bfloat16*)qbf, (const __hip_bfloat16*)wqb, bq, qT, 1024, 0, 0, 0, 1.f);
    gemm_nt<MODE_PROJ_N><<<1024, blk, 0, stream>>>(
        (const __hip_bfloat16*)kbf, (const __hip_bfloat16*)wkb, bk, kp, 1024, 0, 0, 0, 1.f);
    gemm_nt<MODE_PROJ_T><<<1024, blk, 0, stream>>>(
        (const __hip_bfloat16*)vbf, (const __hip_bfloat16*)wvb, bv, vT, 1024, 0, 0, 0, 1.f);

    // scores: per-batch 1024x1024, batch pinned to XCD
    gemm_nt<MODE_SCORES><<<1024, blk, 0, stream>>>(
        (const __hip_bfloat16*)qT, (const __hip_bfloat16*)kp, nullptr, sc, 1024,
        S1M, S1M, S1M, 0.03125f);

    softmax_rows<<<4096, blk, 0, stream>>>(sc, att);

    gemm_nt<MODE_ATT><<<1024, blk, 0, stream>>>(
        (const __hip_bfloat16*)att, (const __hip_bfloat16*)vT, nullptr, ob, 1024,
        S1M, S1M, S1M, 1.f);

    gemm_nt<MODE_OUT><<<1024, blk, 0, stream>>>(
        (const __hip_bfloat16*)ob, (const __hip_bfloat16*)wob, bo, d_out, 1024, 0, 0, 0, 1.f);
}